// Round 13
// baseline (574.466 us; speedup 1.0000x reference)
//
#include <hip/hip_runtime.h>

#define NROWS    262144   // 16 * 16384
#define DIMS     64
#define KCODES   512
#define MTILE    64       // rows per block (8 waves x 8 rows)
#define RPW      8        // rows per wave (amortize e-loads; no-barrier regime)
#define CHUNK    256      // epilogue col-half width (col->lane ownership, frozen)
#define NCHUNK   2        // col halves per lane (8 cols/lane total, frozen)
#define D_PER    16       // dims per x-s_load batch
#define D_CHUNKS 4        // 64 / 16
#define NTHREADS 512

typedef int v8i __attribute__((ext_vector_type(8)));

// DPP lane-xor exchanges (VALU, not DS). quad_perm{1,0,3,2}=0xB1 is exactly
// lane^1; quad_perm{2,3,0,1}=0x4E is exactly lane^2 — same pairing as
// __shfl_xor, so reduction trees using them are bit-identical.
__device__ __forceinline__ float dpp_xor1(float v) {
    int i = __builtin_amdgcn_update_dpp(0, __float_as_int(v), 0xB1, 0xF, 0xF, true);
    return __int_as_float(i);
}
__device__ __forceinline__ float dpp_xor2(float v) {
    int i = __builtin_amdgcn_update_dpp(0, __float_as_int(v), 0x4E, 0xF, 0xF, true);
    return __int_as_float(i);
}

// ---------------------------------------------------------------------------
// prep: embedT[k][d] = embed[d][k]; enorm[k] = sum_d embed[d][k]^2 (numpy
// pairwise-8 order); zero the likelihood accumulator.
// ---------------------------------------------------------------------------
__global__ void prep_kernel(const float* __restrict__ embed,
                            float* __restrict__ embedT,
                            float* __restrict__ enorm,
                            float* __restrict__ lik) {
    int k = blockIdx.x;
    int d = threadIdx.x;
    float v = embed[d * KCODES + k];
    embedT[k * DIMS + d] = v;
    float sq = __fmul_rn(v, v);
    int j = d & 7;
    float r = __shfl(sq, j, 64);
#pragma unroll
    for (int i = 1; i < 8; ++i)
        r = __fadd_rn(r, __shfl(sq, j + 8 * i, 64));
    float t;
    t = __shfl_xor(r, 1, 64); r = __fadd_rn(r, t);
    t = __shfl_xor(r, 2, 64); r = __fadd_rn(r, t);
    t = __shfl_xor(r, 4, 64); r = __fadd_rn(r, t);
    if (d == 0) { enorm[k] = r; lik[k] = 0.0f; }
}

// ---------------------------------------------------------------------------
// main: fused GEMM + softmax + argmax + hard-gather + likelihood partials.
// grid <<<4096, 512>>>. Block: 64 rows x 512 cols; thread owns 8 rows x 8
// cols (acc[2][8][4] = 64 VGPR); wave = 8 full rows (original R0 mapping).
//
// ROUND-13: RPW 4->8 in the R12 no-barrier/no-LDS structure. R12 counters:
// VALU busy 314us (73%), of which ~77us is global-e addressing/issue
// overhead (R9->R12 delta), plus ~200us TA/L1 e-delivery overlapped under
// it. Both scale with e-loads PER OUTPUT ROW -> doubling rows/wave halves
// them (each e dwordx4 now feeds 8 fma instead of 4) and doubles fma ILP.
// R4's RPW=8 failure was a different regime: 32KB LDS + 8 barriers/block
// convoyed waves at VGPR-tier-capped occupancy. Now: zero barriers, 2KB
// LDS, x on the scalar pipe; the ~90-VGPR tier cap (4 waves/SIMD = 50%)
// matches the occupancy we already achieve (45.7%) -> cap shouldn't bind.
// x: one asm batch of 8 s_load_dwordx8 (imm 0..1792 off one SGPR base) +
// in-asm lgkmcnt wait (R9 pattern). e: uniform-base + [cg+k] indexing.
// fma chains ascending-d per accumulator, original 8-row lane mapping,
// R7 epilogue -> bit-identical results.
// Fail criteria (pre-committed): VGPR>128 or WRITE>82MB (spill) -> revert;
// dur>440us -> revert to R12 and declare the fp32 vector-GEMM roofline.
// ---------------------------------------------------------------------------
__launch_bounds__(NTHREADS)
__global__ void main_kernel(const float* __restrict__ x,
                            const float* __restrict__ embed,
                            const float* __restrict__ sigma,
                            const float* __restrict__ embedT,
                            const float* __restrict__ enorm,
                            float* __restrict__ lik,
                            float* __restrict__ out) {
    __shared__ float red_lds[NTHREADS];   // 2 KB, lik reduction only

    const int tid = threadIdx.x;
    const int cg  = tid & 63;        // col group (4 cols per half)
    const int rg  = tid >> 6;        // row group (8 rows), == wave id
    const int rowbase = blockIdx.x * MTILE + rg * RPW;

    const float sigma_v = sigma[0];

    float acc[NCHUNK][RPW][4];
#pragma unroll
    for (int c = 0; c < NCHUNK; ++c)
#pragma unroll
        for (int r = 0; r < RPW; ++r)
#pragma unroll
            for (int q = 0; q < 4; ++q) acc[c][r][q] = 0.0f;

    const float4* __restrict__ eg4 = reinterpret_cast<const float4*>(embed);

    // wave-uniform x base (SGPR): all lanes of this wave share these 8 rows
    const int rg_s = __builtin_amdgcn_readfirstlane(rg);
    const float* xwave = x + (size_t)(blockIdx.x * MTILE + rg_s * RPW) * DIMS;

    for (int dc = 0; dc < D_CHUNKS; ++dc) {
#pragma unroll
        for (int ph = 0; ph < 2; ++ph) {
            // 8 rows x 8 dims (32 B/row) into SGPRs from ONE base with imm
            // offsets (row stride 256 B); wait folded into the asm so every
            // consumer data-depends on completed loads.
            const float* px = xwave + dc * D_PER + ph * 8;
            v8i xs0, xs1, xs2, xs3, xs4, xs5, xs6, xs7;
            asm volatile("s_load_dwordx8 %0, %8, 0\n\t"
                         "s_load_dwordx8 %1, %8, 256\n\t"
                         "s_load_dwordx8 %2, %8, 512\n\t"
                         "s_load_dwordx8 %3, %8, 768\n\t"
                         "s_load_dwordx8 %4, %8, 1024\n\t"
                         "s_load_dwordx8 %5, %8, 1280\n\t"
                         "s_load_dwordx8 %6, %8, 1536\n\t"
                         "s_load_dwordx8 %7, %8, 1792\n\t"
                         "s_waitcnt lgkmcnt(0)"
                         : "=&s"(xs0), "=&s"(xs1), "=&s"(xs2), "=&s"(xs3),
                           "=&s"(xs4), "=&s"(xs5), "=&s"(xs6), "=&s"(xs7)
                         : "s"(px));

            // e: uniform base advancing 4096 B per dim-pair; per-lane part
            // is the loop-invariant cg -> saddr + voffset codegen.
            const float4* ep = eg4 + (size_t)(dc * D_PER + ph * 8) * 128;
#pragma unroll
            for (int d2l = 0; d2l < 4; ++d2l) {   // dim pairs within phase
                float4 e0a = ep[cg];         // dim lo, half 0
                float4 e1a = ep[cg + 128];   // dim hi, half 0
                float4 e0b = ep[cg + 64];    // dim lo, half 1
                float4 e1b = ep[cg + 192];   // dim hi, half 1

#define ROW_FMA(r, xs)                                                        \
                {                                                             \
                    float xlo = __int_as_float(xs[2 * d2l]);                  \
                    float xhi = __int_as_float(xs[2 * d2l + 1]);              \
                    acc[0][r][0] = fmaf(xlo, e0a.x, acc[0][r][0]);            \
                    acc[0][r][1] = fmaf(xlo, e0a.y, acc[0][r][1]);            \
                    acc[0][r][2] = fmaf(xlo, e0a.z, acc[0][r][2]);            \
                    acc[0][r][3] = fmaf(xlo, e0a.w, acc[0][r][3]);            \
                    acc[0][r][0] = fmaf(xhi, e1a.x, acc[0][r][0]);            \
                    acc[0][r][1] = fmaf(xhi, e1a.y, acc[0][r][1]);            \
                    acc[0][r][2] = fmaf(xhi, e1a.z, acc[0][r][2]);            \
                    acc[0][r][3] = fmaf(xhi, e1a.w, acc[0][r][3]);            \
                    acc[1][r][0] = fmaf(xlo, e0b.x, acc[1][r][0]);            \
                    acc[1][r][1] = fmaf(xlo, e0b.y, acc[1][r][1]);            \
                    acc[1][r][2] = fmaf(xlo, e0b.z, acc[1][r][2]);            \
                    acc[1][r][3] = fmaf(xlo, e0b.w, acc[1][r][3]);            \
                    acc[1][r][0] = fmaf(xhi, e1b.x, acc[1][r][0]);            \
                    acc[1][r][1] = fmaf(xhi, e1b.y, acc[1][r][1]);            \
                    acc[1][r][2] = fmaf(xhi, e1b.z, acc[1][r][2]);            \
                    acc[1][r][3] = fmaf(xhi, e1b.w, acc[1][r][3]);            \
                }
                ROW_FMA(0, xs0)
                ROW_FMA(1, xs1)
                ROW_FMA(2, xs2)
                ROW_FMA(3, xs3)
                ROW_FMA(4, xs4)
                ROW_FMA(5, xs5)
                ROW_FMA(6, xs6)
                ROW_FMA(7, xs7)
#undef ROW_FMA
                ep += 256;
            }
        }
    }

    // ---- xnorm for the wave's 8 rows, numpy pairwise-8 order ----
    // lane cg = r_l*8 + j_l computes partial j_l of row r_l (original R0
    // mapping, all 64 lanes unique).
    const int r_l = cg >> 3;
    const int j_l = cg & 7;
    float xr;
    {
        const float* xp = x + (size_t)(rowbase + r_l) * DIMS + j_l;
        float v0 = xp[0];
        float s = __fmul_rn(v0, v0);
#pragma unroll
        for (int i = 1; i < 8; ++i) {
            float v = xp[8 * i];
            s = __fadd_rn(s, __fmul_rn(v, v));
        }
        xr = s;
    }
    {
        float t;
        t = dpp_xor1(xr);          xr = __fadd_rn(xr, t);
        t = dpp_xor2(xr);          xr = __fadd_rn(xr, t);
        t = __shfl_xor(xr, 4, 64); xr = __fadd_rn(xr, t);
    }
    // lane r*8+j now holds xnorm of row r (r = 0..7)

    float en[NCHUNK][4];
#pragma unroll
    for (int c = 0; c < NCHUNK; ++c)
#pragma unroll
        for (int q = 0; q < 4; ++q)
            en[c][q] = enorm[c * CHUNK + cg * 4 + q];

    float likpart[NCHUNK][4];
#pragma unroll
    for (int c = 0; c < NCHUNK; ++c)
#pragma unroll
        for (int q = 0; q < 4; ++q) likpart[c][q] = 0.0f;

#pragma unroll
    for (int r = 0; r < RPW; ++r) {
        float xn = __shfl(xr, r * 8, 64);
        float m = -INFINITY;
#pragma unroll
        for (int c = 0; c < NCHUNK; ++c)
#pragma unroll
            for (int q = 0; q < 4; ++q) {
                float dot  = acc[c][r][q];
                float td   = __fsub_rn(xn, __fmul_rn(2.0f, dot));
                float dist = __fadd_rn(td, en[c][q]);
                float zz   = __fmul_rn(-sigma_v, dist);
                acc[c][r][q] = zz;
                m = fmaxf(m, zz);
            }
        m = fmaxf(m, dpp_xor1(m));
        m = fmaxf(m, dpp_xor2(m));
        m = fmaxf(m, __shfl_xor(m,  4, 64));
        m = fmaxf(m, __shfl_xor(m,  8, 64));
        m = fmaxf(m, __shfl_xor(m, 16, 64));
        m = fmaxf(m, __shfl_xor(m, 32, 64));

        float s = 0.0f;
        int lcol = 1024;
#pragma unroll
        for (int c = 0; c < NCHUNK; ++c)
#pragma unroll
            for (int q = 0; q < 4; ++q) {
                float ee = expf(__fsub_rn(acc[c][r][q], m));
                acc[c][r][q] = ee;
                s += ee;
                int col = c * CHUNK + cg * 4 + q;
                lcol = (ee == 1.0f) ? min(lcol, col) : lcol;
            }
        unsigned long long b0 = __ballot(lcol < CHUNK);
        unsigned long long ba = __ballot(lcol < 1024);
        int srcl = (int)(b0 ? __ffsll(b0) : __ffsll(ba)) - 1;
        int bc = __shfl(lcol, srcl, 64);

        s = __fadd_rn(s, dpp_xor1(s));
        s = __fadd_rn(s, dpp_xor2(s));
        s = __fadd_rn(s, __shfl_xor(s,  4, 64));
        s = __fadd_rn(s, __shfl_xor(s,  8, 64));
        s = __fadd_rn(s, __shfl_xor(s, 16, 64));
        s = __fadd_rn(s, __shfl_xor(s, 32, 64));

        float invS = 1.0f / s;
#pragma unroll
        for (int c = 0; c < NCHUNK; ++c)
#pragma unroll
            for (int q = 0; q < 4; ++q)
                likpart[c][q] = fmaf(acc[c][r][q], invS, likpart[c][q]);

        int row = rowbase + r;
        __builtin_nontemporal_store(embedT[bc * DIMS + cg],
                                    &out[(size_t)row * DIMS + cg]);
    }

    // ---- block-level likelihood reduction ----
    red_lds[tid] = 0.0f;
    __syncthreads();
#pragma unroll
    for (int c = 0; c < NCHUNK; ++c)
#pragma unroll
        for (int q = 0; q < 4; ++q)
            atomicAdd(&red_lds[c * CHUNK + cg * 4 + q], likpart[c][q]);
    __syncthreads();
    atomicAdd(&lik[tid], red_lds[tid]);
}

// ---------------------------------------------------------------------------
// finish: likelihoods = lik_sum / N; quant_loss = 0.25 * mean(p*(log p - log(l+eps)))
// ---------------------------------------------------------------------------
__global__ void finish_kernel(const float* __restrict__ lik,
                              float* __restrict__ out) {
    int tid = threadIdx.x;   // 512 threads
    float l = lik[tid] / 262144.0f;     // exact: divide by 2^18
    out[16777217 + tid] = l;
    const float p = 1.0f / 512.0f;
    float term = __fmul_rn(p, __fsub_rn(logf(p), logf(l + 1e-10f)));
#pragma unroll
    for (int mask = 1; mask < 64; mask <<= 1)
        term += __shfl_xor(term, mask, 64);
    __shared__ float ws[8];
    if ((tid & 63) == 0) ws[tid >> 6] = term;
    __syncthreads();
    if (tid == 0) {
        float ssum = 0.0f;
        for (int i = 0; i < 8; ++i) ssum += ws[i];
        out[16777216] = 0.25f * (ssum / 512.0f);
    }
}

extern "C" void kernel_launch(void* const* d_in, const int* in_sizes, int n_in,
                              void* d_out, int out_size, void* d_ws, size_t ws_size,
                              hipStream_t stream) {
    const float* x     = (const float*)d_in[0];
    const float* embed = (const float*)d_in[1];
    const float* sigma = (const float*)d_in[2];
    float* out = (float*)d_out;
    float* ws  = (float*)d_ws;

    float* embedT = ws;             // 512*64 = 32768 floats
    float* enorm  = ws + 32768;     // 512 floats
    float* lik    = ws + 33280;     // 512 floats

    prep_kernel<<<KCODES, DIMS, 0, stream>>>(embed, embedT, enorm, lik);
    main_kernel<<<NROWS / MTILE, NTHREADS, 0, stream>>>(x, embed, sigma,
                                                        embedT, enorm, lik, out);
    finish_kernel<<<1, NTHREADS, 0, stream>>>(lik, out);
}

// Round 14
// 456.769 us; speedup vs baseline: 1.2577x; 1.2577x over previous
//
#include <hip/hip_runtime.h>

#define NROWS    262144   // 16 * 16384
#define DIMS     64
#define KCODES   512
#define MTILE    32       // rows per block
#define RPW      4        // rows per wave — FROZEN: RPW=8 fails both with
                          // barriers (R4: VGPR 80, occ 24%) and without
                          // (R13: VGPR 84 -> 1 block/CU, occ 23.7%, 567us)
#define CHUNK    256      // epilogue col-half width (col->lane ownership, frozen)
#define NCHUNK   2        // col halves per lane (8 cols/lane total, frozen)
#define D_PER    16       // dims per x-s_load batch
#define D_CHUNKS 4        // 64 / 16
#define NTHREADS 512

typedef int v8i __attribute__((ext_vector_type(8)));

// DPP lane-xor exchanges (VALU, not DS). quad_perm{1,0,3,2}=0xB1 is exactly
// lane^1; quad_perm{2,3,0,1}=0x4E is exactly lane^2 — same pairing as
// __shfl_xor, so reduction trees using them are bit-identical.
__device__ __forceinline__ float dpp_xor1(float v) {
    int i = __builtin_amdgcn_update_dpp(0, __float_as_int(v), 0xB1, 0xF, 0xF, true);
    return __int_as_float(i);
}
__device__ __forceinline__ float dpp_xor2(float v) {
    int i = __builtin_amdgcn_update_dpp(0, __float_as_int(v), 0x4E, 0xF, 0xF, true);
    return __int_as_float(i);
}

// ---------------------------------------------------------------------------
// prep: embedT[k][d] = embed[d][k]; enorm[k] = sum_d embed[d][k]^2 (numpy
// pairwise-8 order); zero the likelihood accumulator.
// ---------------------------------------------------------------------------
__global__ void prep_kernel(const float* __restrict__ embed,
                            float* __restrict__ embedT,
                            float* __restrict__ enorm,
                            float* __restrict__ lik) {
    int k = blockIdx.x;
    int d = threadIdx.x;
    float v = embed[d * KCODES + k];
    embedT[k * DIMS + d] = v;
    float sq = __fmul_rn(v, v);
    int j = d & 7;
    float r = __shfl(sq, j, 64);
#pragma unroll
    for (int i = 1; i < 8; ++i)
        r = __fadd_rn(r, __shfl(sq, j + 8 * i, 64));
    float t;
    t = __shfl_xor(r, 1, 64); r = __fadd_rn(r, t);
    t = __shfl_xor(r, 2, 64); r = __fadd_rn(r, t);
    t = __shfl_xor(r, 4, 64); r = __fadd_rn(r, t);
    if (d == 0) { enorm[k] = r; lik[k] = 0.0f; }
}

// ---------------------------------------------------------------------------
// main: fused GEMM + softmax + argmax + hard-gather + likelihood partials.
// grid <<<8192, 512>>>. Block: 32 rows x 512 cols; thread owns 4 rows x 8
// cols (acc[2][4][4]); wave = 4 full rows.
//
// ROUND-14 = R12 REVERT (best: 429us main-kernel). R13's RPW=8 violated its
// fail criterion (567us): VGPR 84 crossed the 64-reg tier and 8-wave block
// granularity quantized residency to 1 block/CU (occ 23.7%).
//
// Structure summary (the product of 13 rounds of ablation):
// - NO LDS staging, NO GEMM barriers (R12): e is 128KB, L2-resident;
//   eg4[...] is a coalesced 1KB wave-load riding the TA/L1/L2 pipe. All
//   barrier-pipelining attempts lost (R5/R6/R10/R11: occ 66->46).
// - x on the SCALAR pipe (R9): wave-uniform rows via s_load_dwordx8 +
//   in-asm lgkmcnt wait; fma takes the SGPR operand directly.
// - Epilogue (R7): DPP quad_perm for xor1/2 levels, ballot-based
//   first-index argmax via ee==1.0f, in-place z/ev over acc.
// - VGPR 60 <= 64 tier, occ ~46%, VALUBusy ~73%.
// Floor arithmetic: max(VALU ~314us busy, L2 e-delivery ~243us) -> dur 429
// = 73% issue efficiency on the binding pipe; fma-only floor is 109us.
// ---------------------------------------------------------------------------
__launch_bounds__(NTHREADS)
__global__ void main_kernel(const float* __restrict__ x,
                            const float* __restrict__ embed,
                            const float* __restrict__ sigma,
                            const float* __restrict__ embedT,
                            const float* __restrict__ enorm,
                            float* __restrict__ lik,
                            float* __restrict__ out) {
    __shared__ float red_lds[NTHREADS];   // 2 KB, lik reduction only

    const int tid = threadIdx.x;
    const int cg  = tid & 63;        // col group (4 cols per half)
    const int rg  = tid >> 6;        // row group (4 rows), == wave id
    const int rowbase = blockIdx.x * MTILE + rg * RPW;

    const float sigma_v = sigma[0];

    float acc[NCHUNK][RPW][4];
#pragma unroll
    for (int c = 0; c < NCHUNK; ++c)
#pragma unroll
        for (int r = 0; r < RPW; ++r)
#pragma unroll
            for (int q = 0; q < 4; ++q) acc[c][r][q] = 0.0f;

    const float4* __restrict__ eg4 = reinterpret_cast<const float4*>(embed);

    // wave-uniform x base (SGPR): all lanes of this wave share these 4 rows
    const int rg_s = __builtin_amdgcn_readfirstlane(rg);
    const float* xwave = x + (size_t)(blockIdx.x * MTILE + rg_s * RPW) * DIMS;

    for (int dc = 0; dc < D_CHUNKS; ++dc) {
#pragma unroll
        for (int ph = 0; ph < 2; ++ph) {
            // 4 rows x 8 dims (32 B/row) into SGPRs; wait folded into the
            // asm so every consumer data-depends on completed loads.
            const float* p0 = xwave + 0 * DIMS + dc * D_PER + ph * 8;
            const float* p1 = xwave + 1 * DIMS + dc * D_PER + ph * 8;
            const float* p2 = xwave + 2 * DIMS + dc * D_PER + ph * 8;
            const float* p3 = xwave + 3 * DIMS + dc * D_PER + ph * 8;
            v8i xs0, xs1, xs2, xs3;
            asm volatile("s_load_dwordx8 %0, %4, 0\n\t"
                         "s_load_dwordx8 %1, %5, 0\n\t"
                         "s_load_dwordx8 %2, %6, 0\n\t"
                         "s_load_dwordx8 %3, %7, 0\n\t"
                         "s_waitcnt lgkmcnt(0)"
                         : "=&s"(xs0), "=&s"(xs1), "=&s"(xs2), "=&s"(xs3)
                         : "s"(p0), "s"(p1), "s"(p2), "s"(p3));

#pragma unroll
            for (int d2l = 0; d2l < 4; ++d2l) {   // dim pairs within phase
                const int d2  = ph * 4 + d2l;
                const int dlo = dc * D_PER + 2 * d2;   // global dim (even)
                // e direct from global: coalesced 1KB wave-loads, L1/L2-hit
                float4 e0a = eg4[(size_t)(dlo + 0) * 128 +  0 + cg];  // lo,h0
                float4 e1a = eg4[(size_t)(dlo + 1) * 128 +  0 + cg];  // hi,h0
                float4 e0b = eg4[(size_t)(dlo + 0) * 128 + 64 + cg];  // lo,h1
                float4 e1b = eg4[(size_t)(dlo + 1) * 128 + 64 + cg];  // hi,h1

#define ROW_FMA(r, xs)                                                        \
                {                                                             \
                    float xlo = __int_as_float(xs[2 * d2l]);                  \
                    float xhi = __int_as_float(xs[2 * d2l + 1]);              \
                    acc[0][r][0] = fmaf(xlo, e0a.x, acc[0][r][0]);            \
                    acc[0][r][1] = fmaf(xlo, e0a.y, acc[0][r][1]);            \
                    acc[0][r][2] = fmaf(xlo, e0a.z, acc[0][r][2]);            \
                    acc[0][r][3] = fmaf(xlo, e0a.w, acc[0][r][3]);            \
                    acc[0][r][0] = fmaf(xhi, e1a.x, acc[0][r][0]);            \
                    acc[0][r][1] = fmaf(xhi, e1a.y, acc[0][r][1]);            \
                    acc[0][r][2] = fmaf(xhi, e1a.z, acc[0][r][2]);            \
                    acc[0][r][3] = fmaf(xhi, e1a.w, acc[0][r][3]);            \
                    acc[1][r][0] = fmaf(xlo, e0b.x, acc[1][r][0]);            \
                    acc[1][r][1] = fmaf(xlo, e0b.y, acc[1][r][1]);            \
                    acc[1][r][2] = fmaf(xlo, e0b.z, acc[1][r][2]);            \
                    acc[1][r][3] = fmaf(xlo, e0b.w, acc[1][r][3]);            \
                    acc[1][r][0] = fmaf(xhi, e1b.x, acc[1][r][0]);            \
                    acc[1][r][1] = fmaf(xhi, e1b.y, acc[1][r][1]);            \
                    acc[1][r][2] = fmaf(xhi, e1b.z, acc[1][r][2]);            \
                    acc[1][r][3] = fmaf(xhi, e1b.w, acc[1][r][3]);            \
                }
                ROW_FMA(0, xs0)
                ROW_FMA(1, xs1)
                ROW_FMA(2, xs2)
                ROW_FMA(3, xs3)
#undef ROW_FMA
            }
        }
    }

    // ---- xnorm for the wave's 4 rows, numpy pairwise-8 order ----
    const int r_l = (cg >> 3) & 3;
    const int j_l = cg & 7;
    float xr;
    {
        const float* xp = x + (size_t)(rowbase + r_l) * DIMS + j_l;
        float v0 = xp[0];
        float s = __fmul_rn(v0, v0);
#pragma unroll
        for (int i = 1; i < 8; ++i) {
            float v = xp[8 * i];
            s = __fadd_rn(s, __fmul_rn(v, v));
        }
        xr = s;
    }
    {
        float t;
        t = dpp_xor1(xr);          xr = __fadd_rn(xr, t);
        t = dpp_xor2(xr);          xr = __fadd_rn(xr, t);
        t = __shfl_xor(xr, 4, 64); xr = __fadd_rn(xr, t);
    }

    float en[NCHUNK][4];
#pragma unroll
    for (int c = 0; c < NCHUNK; ++c)
#pragma unroll
        for (int q = 0; q < 4; ++q)
            en[c][q] = enorm[c * CHUNK + cg * 4 + q];

    float likpart[NCHUNK][4];
#pragma unroll
    for (int c = 0; c < NCHUNK; ++c)
#pragma unroll
        for (int q = 0; q < 4; ++q) likpart[c][q] = 0.0f;

#pragma unroll
    for (int r = 0; r < RPW; ++r) {
        float xn = __shfl(xr, r * 8, 64);
        float m = -INFINITY;
#pragma unroll
        for (int c = 0; c < NCHUNK; ++c)
#pragma unroll
            for (int q = 0; q < 4; ++q) {
                float dot  = acc[c][r][q];
                float td   = __fsub_rn(xn, __fmul_rn(2.0f, dot));
                float dist = __fadd_rn(td, en[c][q]);
                float zz   = __fmul_rn(-sigma_v, dist);
                acc[c][r][q] = zz;
                m = fmaxf(m, zz);
            }
        m = fmaxf(m, dpp_xor1(m));
        m = fmaxf(m, dpp_xor2(m));
        m = fmaxf(m, __shfl_xor(m,  4, 64));
        m = fmaxf(m, __shfl_xor(m,  8, 64));
        m = fmaxf(m, __shfl_xor(m, 16, 64));
        m = fmaxf(m, __shfl_xor(m, 32, 64));

        float s = 0.0f;
        int lcol = 1024;
#pragma unroll
        for (int c = 0; c < NCHUNK; ++c)
#pragma unroll
            for (int q = 0; q < 4; ++q) {
                float ee = expf(__fsub_rn(acc[c][r][q], m));
                acc[c][r][q] = ee;
                s += ee;
                int col = c * CHUNK + cg * 4 + q;
                lcol = (ee == 1.0f) ? min(lcol, col) : lcol;
            }
        unsigned long long b0 = __ballot(lcol < CHUNK);
        unsigned long long ba = __ballot(lcol < 1024);
        int srcl = (int)(b0 ? __ffsll(b0) : __ffsll(ba)) - 1;
        int bc = __shfl(lcol, srcl, 64);

        s = __fadd_rn(s, dpp_xor1(s));
        s = __fadd_rn(s, dpp_xor2(s));
        s = __fadd_rn(s, __shfl_xor(s,  4, 64));
        s = __fadd_rn(s, __shfl_xor(s,  8, 64));
        s = __fadd_rn(s, __shfl_xor(s, 16, 64));
        s = __fadd_rn(s, __shfl_xor(s, 32, 64));

        float invS = 1.0f / s;
#pragma unroll
        for (int c = 0; c < NCHUNK; ++c)
#pragma unroll
            for (int q = 0; q < 4; ++q)
                likpart[c][q] = fmaf(acc[c][r][q], invS, likpart[c][q]);

        int row = rowbase + r;
        __builtin_nontemporal_store(embedT[bc * DIMS + cg],
                                    &out[(size_t)row * DIMS + cg]);
    }

    // ---- block-level likelihood reduction ----
    red_lds[tid] = 0.0f;
    __syncthreads();
#pragma unroll
    for (int c = 0; c < NCHUNK; ++c)
#pragma unroll
        for (int q = 0; q < 4; ++q)
            atomicAdd(&red_lds[c * CHUNK + cg * 4 + q], likpart[c][q]);
    __syncthreads();
    atomicAdd(&lik[tid], red_lds[tid]);
}

// ---------------------------------------------------------------------------
// finish: likelihoods = lik_sum / N; quant_loss = 0.25 * mean(p*(log p - log(l+eps)))
// ---------------------------------------------------------------------------
__global__ void finish_kernel(const float* __restrict__ lik,
                              float* __restrict__ out) {
    int tid = threadIdx.x;   // 512 threads
    float l = lik[tid] / 262144.0f;     // exact: divide by 2^18
    out[16777217 + tid] = l;
    const float p = 1.0f / 512.0f;
    float term = __fmul_rn(p, __fsub_rn(logf(p), logf(l + 1e-10f)));
#pragma unroll
    for (int mask = 1; mask < 64; mask <<= 1)
        term += __shfl_xor(term, mask, 64);
    __shared__ float ws[8];
    if ((tid & 63) == 0) ws[tid >> 6] = term;
    __syncthreads();
    if (tid == 0) {
        float ssum = 0.0f;
        for (int i = 0; i < 8; ++i) ssum += ws[i];
        out[16777216] = 0.25f * (ssum / 512.0f);
    }
}

extern "C" void kernel_launch(void* const* d_in, const int* in_sizes, int n_in,
                              void* d_out, int out_size, void* d_ws, size_t ws_size,
                              hipStream_t stream) {
    const float* x     = (const float*)d_in[0];
    const float* embed = (const float*)d_in[1];
    const float* sigma = (const float*)d_in[2];
    float* out = (float*)d_out;
    float* ws  = (float*)d_ws;

    float* embedT = ws;             // 512*64 = 32768 floats
    float* enorm  = ws + 32768;     // 512 floats
    float* lik    = ws + 33280;     // 512 floats

    prep_kernel<<<KCODES, DIMS, 0, stream>>>(embed, embedT, enorm, lik);
    main_kernel<<<NROWS / MTILE, NTHREADS, 0, stream>>>(x, embed, sigma,
                                                        embedT, enorm, lik, out);
    finish_kernel<<<1, NTHREADS, 0, stream>>>(lik, out);
}